// Round 7
// baseline (522.907 us; speedup 1.0000x reference)
//
#include <hip/hip_runtime.h>
#include <hip/hip_bf16.h>
#include <math.h>

// N=50000, E=400000, F_IN=128, HID=64, OUT=40, H=4
#define SLOPE 0.2f
#define LOG2E 1.44269504088896f

typedef unsigned short bf16_t;
typedef short bh8 __attribute__((ext_vector_type(8)));
typedef float f32x4 __attribute__((ext_vector_type(4)));

__device__ __forceinline__ float bf2f(bf16_t x) {
    return __uint_as_float((unsigned)x << 16);
}
__device__ __forceinline__ bf16_t f2bf(float v) {
    unsigned u = __float_as_uint(v);
    return (bf16_t)((u + 0x7FFFu + ((u >> 16) & 1u)) >> 16);  // RNE
}
__device__ __forceinline__ ushort2 pk_f2bf(float a, float b) {
    __hip_bfloat162 h2 = __float22bfloat162_rn(float2{a, b});  // v_cvt_pk_bf16_f32
    union { __hip_bfloat162 h; ushort2 u; } u;
    u.h = h2;
    return u.u;
}

// ---------------- CSR build (verified R2-R6) ----------------

__global__ void hist_dst(const int* __restrict__ dst, int E, int* __restrict__ deg) {
    int e = blockIdx.x * 256 + threadIdx.x;
    if (e < E) atomicAdd(&deg[dst[e]], 1);
}

__global__ void deg_chunk_sum(const int* __restrict__ deg, int n, int* __restrict__ chunk_sums) {
    __shared__ int sm[256];
    int base = blockIdx.x * 1024;
    int s = 0;
    for (int i = threadIdx.x; i < 1024; i += 256) {
        int idx = base + i;
        if (idx < n) s += deg[idx];
    }
    sm[threadIdx.x] = s;
    __syncthreads();
    for (int off = 128; off > 0; off >>= 1) {
        if (threadIdx.x < off) sm[threadIdx.x] += sm[threadIdx.x + off];
        __syncthreads();
    }
    if (threadIdx.x == 0) chunk_sums[blockIdx.x] = sm[0];
}

__global__ void scan_chunk_sums(int* __restrict__ chunk_sums, int nchunks) {
    __shared__ int sm[256];
    int t = threadIdx.x;
    if (t < nchunks) sm[t] = chunk_sums[t];
    __syncthreads();
    if (t == 0) {
        int run = 0;
        for (int i = 0; i < nchunks; i++) { int v = sm[i]; sm[i] = run; run += v; }
    }
    __syncthreads();
    if (t < nchunks) chunk_sums[t] = sm[t];
}

__global__ void scan_write(const int* __restrict__ deg, int n,
                           const int* __restrict__ chunk_sums,
                           int* __restrict__ row_start, int Etot) {
    int base = blockIdx.x * 1024;
    int t = threadIdx.x;
    int v[4];
    int tsum = 0;
#pragma unroll
    for (int j = 0; j < 4; j++) {
        int idx = base + t * 4 + j;
        v[j] = (idx < n) ? deg[idx] : 0;
        tsum += v[j];
    }
    __shared__ int sm[256];
    sm[t] = tsum;
    __syncthreads();
    for (int off = 1; off < 256; off <<= 1) {
        int x = (t >= off) ? sm[t - off] : 0;
        __syncthreads();
        sm[t] += x;
        __syncthreads();
    }
    int excl = sm[t] - tsum + chunk_sums[blockIdx.x];
#pragma unroll
    for (int j = 0; j < 4; j++) {
        int idx = base + t * 4 + j;
        if (idx < n) row_start[idx] = excl;
        excl += v[j];
    }
    if (blockIdx.x == 0 && t == 0) row_start[n] = Etot;
}

__global__ void scatter_edges(const int* __restrict__ dst, const int* __restrict__ src, int E,
                              const int* __restrict__ row_start,
                              int* __restrict__ fill, int* __restrict__ src_sorted) {
    int e = blockIdx.x * 256 + threadIdx.x;
    if (e < E) {
        int d_ = dst[e];
        int pos = row_start[d_] + atomicAdd(&fill[d_], 1);
        src_sorted[pos] = src[e];
    }
}

// ---------------- weight conversion: W[K][Nc] f32 -> Wt[Npad][K] bf16 (verified R3) ----------------

__global__ void convert_weights(
    const float* __restrict__ w0, const float* __restrict__ w1, const float* __restrict__ w2,
    const float* __restrict__ w3, const float* __restrict__ w4,
    const float* __restrict__ w5, const float* __restrict__ w6,
    const float* __restrict__ wr2, const float* __restrict__ br2,
    bf16_t* __restrict__ t0, bf16_t* __restrict__ t1, bf16_t* __restrict__ t2,
    bf16_t* __restrict__ t3, bf16_t* __restrict__ t4,
    bf16_t* __restrict__ t5, bf16_t* __restrict__ t6,
    bf16_t* __restrict__ teff, float* __restrict__ b_eff)
{
    int b = blockIdx.x, t = threadIdx.x;
    const float* W; bf16_t* T; int K, Nc, lb;
    if (b < 384) {
        int g = b / 128; lb = b - g * 128;
        W = g == 0 ? w0 : (g == 1 ? w1 : w2);
        T = g == 0 ? t0 : (g == 1 ? t1 : t2);
        K = 128; Nc = 256;
    } else if (b < 896) {
        int g = (b - 384) / 256; lb = (b - 384) - g * 256;
        W = g == 0 ? w3 : w4; T = g == 0 ? t3 : t4;
        K = 256; Nc = 256;
    } else if (b < 1280) {
        int g = (b - 896) / 192; lb = (b - 896) - g * 192;
        W = g == 0 ? w5 : w6; T = g == 0 ? t5 : t6;
        K = 256; Nc = 160;
    } else {
        lb = b - 1280;
        int idx = lb * 256 + t;          // 64*256 = 16384 elems
        int n = idx >> 8, k = idx & 255;
        float v = 0.f;
        if (n < 40)
            v = 0.25f * (wr2[(size_t)k * 160 + n] + wr2[(size_t)k * 160 + 40 + n] +
                         wr2[(size_t)k * 160 + 80 + n] + wr2[(size_t)k * 160 + 120 + n]);
        teff[idx] = f2bf(v);
        if (lb == 0 && t < 40)
            b_eff[t] = 0.25f * (br2[t] + br2[40 + t] + br2[80 + t] + br2[120 + t]);
        return;
    }
    int idx = lb * 256 + t;
    int n = idx / K, k = idx - n * K;
    float v = (n < Nc) ? W[(size_t)k * Nc + n] : 0.f;
    T[idx] = f2bf(v);
}

// ---------------- A-in-LDS multi-output MFMA GEMM (R6 structure, verified) ----------------
// HAS_EFF: waves of block.x==0 with w<2 additionally compute the folded
// residual GEMM (Wte 64x256 -> Ce f32 [M,40], full overwrite incl. bias);
// a later FINAL aggregate accumulates onto it.

template <typename TA, int NOUT, int KTOT, bool SPLIT40, bool HAS_EFF>
__global__ __launch_bounds__(256) void gemm_lds(
    const TA* __restrict__ A,
    const bf16_t* __restrict__ Wt0, const bf16_t* __restrict__ Wt1, const bf16_t* __restrict__ Wt2,
    const float* __restrict__ bias0, const float* __restrict__ bias1, const float* __restrict__ bias2,
    bf16_t* __restrict__ C0, bf16_t* __restrict__ C1, bf16_t* __restrict__ C2,
    const bf16_t* __restrict__ Wte, const float* __restrict__ biase, float* __restrict__ Ce,
    int M, int Nc, int Npad)
{
    constexpr int LSTR = KTOT + ((KTOT == 128) ? 40 : 24);
    __shared__ bf16_t As[64 * LSTR];

    int tid = threadIdx.x;
    int lane = tid & 63, w = tid >> 6;
    int lm = lane & 15, lq = lane >> 4;
    int m0 = blockIdx.y * 64;
    int n0 = blockIdx.x * 128 + w * 32;
    if (n0 > Npad - 32) n0 = Npad - 32;   // clamped waves duplicate work; stores guarded

    const bf16_t* Wts[3] = {Wt0, Wt1, Wt2};
    const float* biases[3] = {bias0, bias1, bias2};
    bf16_t* Cs[3] = {C0, C1, C2};

    // ---- stage A slab (64 rows x KTOT) ----
    if (sizeof(TA) == 4) {            // KTOT == 128, f32 input
#pragma unroll
        for (int it = 0; it < 4; it++) {
            int idx = tid + it * 256;  // 1024 chunks of 8 floats
            int r = idx >> 4, c = idx & 15;
            int gm = m0 + r; if (gm >= M) gm = M - 1;
            const float* ap = (const float*)A + (size_t)gm * KTOT + c * 8;
            float4 lo = *(const float4*)ap;
            float4 hi = *(const float4*)(ap + 4);
            ushort2 p0 = pk_f2bf(lo.x, lo.y), p1 = pk_f2bf(lo.z, lo.w);
            ushort2 p2 = pk_f2bf(hi.x, hi.y), p3 = pk_f2bf(hi.z, hi.w);
            bh8 v = { (short)p0.x, (short)p0.y, (short)p1.x, (short)p1.y,
                      (short)p2.x, (short)p2.y, (short)p3.x, (short)p3.y };
            *(bh8*)(As + r * LSTR + c * 8) = v;
        }
    } else {                           // KTOT == 256, bf16 input
#pragma unroll
        for (int it = 0; it < 8; it++) {
            int idx = tid + it * 256;  // 2048 chunks of 8 bf16
            int r = idx >> 5, c = idx & 31;
            int gm = m0 + r; if (gm >= M) gm = M - 1;
            bh8 v = *(const bh8*)((const bf16_t*)A + (size_t)gm * KTOT + c * 8);
            *(bh8*)(As + r * LSTR + c * 8) = v;
        }
    }

    int boff[NOUT][2];
#pragma unroll
    for (int o = 0; o < NOUT; o++)
#pragma unroll
        for (int nt = 0; nt < 2; nt++)
            boff[o][nt] = (n0 + nt * 16 + lm) * KTOT + lq * 8;

    f32x4 acc[NOUT][4][2];
#pragma unroll
    for (int o = 0; o < NOUT; o++)
#pragma unroll
        for (int i = 0; i < 4; i++)
#pragma unroll
            for (int j = 0; j < 2; j++)
                acc[o][i][j] = (f32x4){0.f, 0.f, 0.f, 0.f};

    bool eff_active = HAS_EFF && (blockIdx.x == 0) && (w < 2);
    f32x4 acc_e[4][2];
    int beoff[2];
    if (HAS_EFF) {
#pragma unroll
        for (int i = 0; i < 4; i++)
#pragma unroll
            for (int j = 0; j < 2; j++)
                acc_e[i][j] = (f32x4){0.f, 0.f, 0.f, 0.f};
#pragma unroll
        for (int nt = 0; nt < 2; nt++)
            beoff[nt] = (w * 32 + nt * 16 + lm) * KTOT + lq * 8;
    }

    __syncthreads();

    // ---- K loop: A from LDS, B from global (L2-resident) ----
#pragma unroll
    for (int kc = 0; kc < KTOT / 32; kc++) {
        bh8 af[4];
#pragma unroll
        for (int mt = 0; mt < 4; mt++)
            af[mt] = *(const bh8*)(As + (mt * 16 + lm) * LSTR + kc * 32 + lq * 8);
#pragma unroll
        for (int o = 0; o < NOUT; o++) {
            bh8 bf[2];
#pragma unroll
            for (int nt = 0; nt < 2; nt++)
                bf[nt] = *(const bh8*)(Wts[o] + boff[o][nt] + kc * 32);
#pragma unroll
            for (int mt = 0; mt < 4; mt++)
#pragma unroll
                for (int nt = 0; nt < 2; nt++)
                    acc[o][mt][nt] = __builtin_amdgcn_mfma_f32_16x16x32_bf16(af[mt], bf[nt], acc[o][mt][nt], 0, 0, 0);
        }
        if (HAS_EFF) {
            if (eff_active) {
                bh8 be[2];
#pragma unroll
                for (int nt = 0; nt < 2; nt++)
                    be[nt] = *(const bh8*)(Wte + beoff[nt] + kc * 32);
#pragma unroll
                for (int mt = 0; mt < 4; mt++)
#pragma unroll
                    for (int nt = 0; nt < 2; nt++)
                        acc_e[mt][nt] = __builtin_amdgcn_mfma_f32_16x16x32_bf16(af[mt], be[nt], acc_e[mt][nt], 0, 0, 0);
            }
        }
    }

    // ---- eff epilogue (f32, direct stores; no LDS use) ----
    if (HAS_EFF && eff_active) {
#pragma unroll
        for (int nt = 0; nt < 2; nt++) {
            int gn = w * 32 + nt * 16 + lm;
            if (gn >= 40) continue;
            float bv = biase[gn];
#pragma unroll
            for (int mt = 0; mt < 4; mt++)
#pragma unroll
                for (int r = 0; r < 4; r++) {
                    int gm = m0 + mt * 16 + lq * 4 + r;
                    if (gm < M) Ce[(size_t)gm * 40 + gn] = acc_e[mt][nt][r] + bv;
                }
        }
    }

    __syncthreads();   // all waves done reading A-slab; LDS reused by epilogue

    // ---- bf16 epilogue via LDS round-trip -> full-line stores ----
    bf16_t* ep = As + w * (64 * 40);
#pragma unroll
    for (int o = 0; o < NOUT; o++) {
#pragma unroll
        for (int nt = 0; nt < 2; nt++) {
            int gn = n0 + nt * 16 + lm;
            float bv = (gn < Nc) ? biases[o][gn] : 0.f;
#pragma unroll
            for (int mt = 0; mt < 4; mt++)
#pragma unroll
                for (int r = 0; r < 4; r++)
                    ep[(mt * 16 + lq * 4 + r) * 40 + nt * 16 + lm] = f2bf(acc[o][mt][nt][r] + bv);
        }
#pragma unroll
        for (int it = 0; it < 4; it++) {
            int row = it * 16 + (lane >> 2);
            int cc = (lane & 3) * 8;
            bh8 v = *(const bh8*)(ep + row * 40 + cc);
            int gm = m0 + row;
            int cg = n0 + cc;
            if (gm < M && cg < Nc) {
                size_t cb = SPLIT40 ? (size_t)(cg + 24 * (cg / 40)) : (size_t)cg;
                size_t rs = SPLIT40 ? 256 : (size_t)Nc;
                *(bh8*)(Cs[o] + (size_t)gm * rs + cb) = v;
            }
        }
    }
}

// ---------------- GATv2 aggregation: one WAVE per node, 4 chains, BRANCHLESS base-2 ----------------
// attn is pre-scaled by log2e at load -> logits live in base-2 domain;
// exp2(logit2 - m2) == exp(logit - m), so softmax weights are identical.

__device__ __forceinline__ float edge_logit(const float h[4], const float hdf[4], const float at[4]) {
    float p = 0.f;
#pragma unroll
    for (int j = 0; j < 4; j++) {
        float q = h[j] + hdf[j];
        float lr = q > 0.f ? q : SLOPE * q;
        p += lr * at[j];
    }
    p += __shfl_xor(p, 1, 64);
    p += __shfl_xor(p, 2, 64);
    p += __shfl_xor(p, 4, 64);
    p += __shfl_xor(p, 8, 64);
    return p;
}

__device__ __forceinline__ void chain_update(float logit, const float h[4],
                                             float& m, float& l, float* a) {
    float nm = fmaxf(m, logit);
    float eo = exp2f(m - nm);      // m=-inf first time -> 0
    float en = exp2f(logit - nm);
    l = l * eo + en;
#pragma unroll
    for (int j = 0; j < 4; j++) a[j] = a[j] * eo + en * h[j];
    m = nm;
}

template <int DVALID, bool FINAL, bool RES_INPLACE>
__global__ __launch_bounds__(256) void gat_agg_wave(
    const bf16_t* __restrict__ hs, const bf16_t* __restrict__ hd,
    const float* __restrict__ attn,
    const int* __restrict__ row_start, const int* __restrict__ src_sorted,
    bf16_t* __restrict__ P, float* __restrict__ out_final, int N)
{
    int w = threadIdx.x >> 6, l = threadIdx.x & 63;
    int n = blockIdx.x * 4 + w;
    if (n >= N) return;
    int h = l >> 4;
    int f0 = 4 * l;
    int dp = 4 * (l & 15);

    float at[4];
#pragma unroll
    for (int j = 0; j < 4; j++)
        at[j] = (dp + j < DVALID) ? attn[h * DVALID + dp + j] * LOG2E : 0.f;
    ushort4 hv = *(const ushort4*)(hd + (size_t)n * 256 + f0);
    float hdf[4] = { bf2f(hv.x), bf2f(hv.y), bf2f(hv.z), bf2f(hv.w) };

    int s = row_start[n], e = row_start[n + 1];

    float cm[4] = {-INFINITY, -INFINITY, -INFINITY, -INFINITY};
    float cl[4] = {0.f, 0.f, 0.f, 0.f};
    float ca[4][4] = {};

    int i = s;
    for (; i + 4 <= e; i += 4) {
        int sn0 = src_sorted[i], sn1 = src_sorted[i + 1];
        int sn2 = src_sorted[i + 2], sn3 = src_sorted[i + 3];
        ushort4 r0 = *(const ushort4*)(hs + (size_t)sn0 * 256 + f0);
        ushort4 r1 = *(const ushort4*)(hs + (size_t)sn1 * 256 + f0);
        ushort4 r2 = *(const ushort4*)(hs + (size_t)sn2 * 256 + f0);
        ushort4 r3 = *(const ushort4*)(hs + (size_t)sn3 * 256 + f0);
        float h0[4] = { bf2f(r0.x), bf2f(r0.y), bf2f(r0.z), bf2f(r0.w) };
        float h1[4] = { bf2f(r1.x), bf2f(r1.y), bf2f(r1.z), bf2f(r1.w) };
        float h2[4] = { bf2f(r2.x), bf2f(r2.y), bf2f(r2.z), bf2f(r2.w) };
        float h3[4] = { bf2f(r3.x), bf2f(r3.y), bf2f(r3.z), bf2f(r3.w) };
        float p0 = edge_logit(h0, hdf, at);
        float p1 = edge_logit(h1, hdf, at);
        float p2 = edge_logit(h2, hdf, at);
        float p3 = edge_logit(h3, hdf, at);
        chain_update(p0, h0, cm[0], cl[0], ca[0]);
        chain_update(p1, h1, cm[1], cl[1], ca[1]);
        chain_update(p2, h2, cm[2], cl[2], ca[2]);
        chain_update(p3, h3, cm[3], cl[3], ca[3]);
    }
    for (; i < e; i++) {
        int sn0 = src_sorted[i];
        ushort4 r0 = *(const ushort4*)(hs + (size_t)sn0 * 256 + f0);
        float h0[4] = { bf2f(r0.x), bf2f(r0.y), bf2f(r0.z), bf2f(r0.w) };
        float p0 = edge_logit(h0, hdf, at);
        chain_update(p0, h0, cm[0], cl[0], ca[0]);
    }

    float v[4] = {0.f, 0.f, 0.f, 0.f};
    if (e > s) {
        float M = fmaxf(fmaxf(cm[0], cm[1]), fmaxf(cm[2], cm[3]));
        float L = 0.f;
#pragma unroll
        for (int c = 0; c < 4; c++) {
            float sc = exp2f(cm[c] - M);   // empty chain: exp2(-inf)=0
            L += sc * cl[c];
#pragma unroll
            for (int j = 0; j < 4; j++) v[j] += sc * ca[c][j];
        }
        float inv = 1.f / L;
#pragma unroll
        for (int j = 0; j < 4; j++) v[j] *= inv;
    }

    if (FINAL) {
#pragma unroll
        for (int j = 0; j < 4; j++) {
            v[j] += __shfl_xor(v[j], 16, 64);
            v[j] += __shfl_xor(v[j], 32, 64);
        }
        if (l < DVALID / 4) {
            float4* op = (float4*)(out_final + (size_t)n * DVALID + 4 * l);
            float4 cur = *op;
            cur.x += 0.25f * v[0]; cur.y += 0.25f * v[1];
            cur.z += 0.25f * v[2]; cur.w += 0.25f * v[3];
            *op = cur;
        }
    } else {
        size_t oi = (size_t)n * 256 + f0;
        if (RES_INPLACE) {
            ushort4 pv = *(const ushort4*)(P + oi);
            v[0] += bf2f(pv.x); v[1] += bf2f(pv.y);
            v[2] += bf2f(pv.z); v[3] += bf2f(pv.w);
        }
        ushort4 ov = { f2bf(v[0]), f2bf(v[1]), f2bf(v[2]), f2bf(v[3]) };
        *(ushort4*)(P + oi) = ov;
    }
}

// ---------------- launch ----------------

extern "C" void kernel_launch(void* const* d_in, const int* in_sizes, int n_in,
                              void* d_out, int out_size, void* d_ws, size_t ws_size,
                              hipStream_t stream) {
    const float* x0    = (const float*)d_in[0];
    const int*   src   = (const int*)d_in[1];
    const int*   dst   = (const int*)d_in[2];
    const float* w_src0 = (const float*)d_in[3];  const float* b_src0 = (const float*)d_in[4];
    const float* w_dst0 = (const float*)d_in[5];  const float* b_dst0 = (const float*)d_in[6];
    const float* attn0  = (const float*)d_in[7];
    const float* w_res0 = (const float*)d_in[8];  const float* b_res0 = (const float*)d_in[9];
    const float* w_src1 = (const float*)d_in[10]; const float* b_src1 = (const float*)d_in[11];
    const float* w_dst1 = (const float*)d_in[12]; const float* b_dst1 = (const float*)d_in[13];
    const float* attn1  = (const float*)d_in[14];
    const float* w_src2 = (const float*)d_in[15]; const float* b_src2 = (const float*)d_in[16];
    const float* w_dst2 = (const float*)d_in[17]; const float* b_dst2 = (const float*)d_in[18];
    const float* attn2  = (const float*)d_in[19];
    const float* w_res2 = (const float*)d_in[20]; const float* b_res2 = (const float*)d_in[21];

    const int N = in_sizes[0] / 128;   // 50000
    const int E = in_sizes[1];         // 400000
    float* out = (float*)d_out;
    (void)n_in; (void)out_size; (void)ws_size;

    // ---- workspace (~80 MB) ----
    char* ws = (char*)d_ws;
    size_t off = 0;
    auto alloc = [&](size_t bytes) {
        void* q = ws + off;
        off = (off + bytes + 255) & ~(size_t)255;
        return q;
    };
    int* deg        = (int*)alloc((size_t)2 * N * 4);
    int* fill       = deg + N;
    int* row_start  = (int*)alloc((size_t)(N + 1) * 4);
    int* chunk_sums = (int*)alloc(256 * 4);
    int* src_sorted = (int*)alloc((size_t)E * 4);
    bf16_t* t_src0 = (bf16_t*)alloc(256 * 128 * 2);
    bf16_t* t_dst0 = (bf16_t*)alloc(256 * 128 * 2);
    bf16_t* t_res0 = (bf16_t*)alloc(256 * 128 * 2);
    bf16_t* t_src1 = (bf16_t*)alloc(256 * 256 * 2);
    bf16_t* t_dst1 = (bf16_t*)alloc(256 * 256 * 2);
    bf16_t* t_src2 = (bf16_t*)alloc(192 * 256 * 2);
    bf16_t* t_dst2 = (bf16_t*)alloc(192 * 256 * 2);
    bf16_t* t_eff  = (bf16_t*)alloc(64 * 256 * 2);
    float*  b_eff  = (float*)alloc(64 * 4);
    const size_t elems = (size_t)N * 256;
    bf16_t* P  = (bf16_t*)alloc(elems * 2);
    bf16_t* HS = (bf16_t*)alloc(elems * 2);
    bf16_t* HD = (bf16_t*)alloc(elems * 2);

    // ---- CSR build + weight conversion ----
    hipMemsetAsync(deg, 0, (size_t)2 * N * 4, stream);
    int eblocks = (E + 255) / 256;
    int nchunks = (N + 1023) / 1024;
    hipLaunchKernelGGL(hist_dst, dim3(eblocks), dim3(256), 0, stream, dst, E, deg);
    hipLaunchKernelGGL(convert_weights, dim3(1344), dim3(256), 0, stream,
                       w_src0, w_dst0, w_res0, w_src1, w_dst1, w_src2, w_dst2, w_res2, b_res2,
                       t_src0, t_dst0, t_res0, t_src1, t_dst1, t_src2, t_dst2, t_eff, b_eff);
    hipLaunchKernelGGL(deg_chunk_sum, dim3(nchunks), dim3(256), 0, stream, deg, N, chunk_sums);
    hipLaunchKernelGGL(scan_chunk_sums, dim3(1), dim3(256), 0, stream, chunk_sums, nchunks);
    hipLaunchKernelGGL(scan_write, dim3(nchunks), dim3(256), 0, stream, deg, N, chunk_sums, row_start, E);
    hipLaunchKernelGGL(scatter_edges, dim3(eblocks), dim3(256), 0, stream, dst, src, E, row_start, fill, src_sorted);

    dim3 blk(256);
    int mtiles = (N + 63) / 64;        // 782
    int ab = (N + 3) / 4;              // 12500 (wave-per-node agg)

    // ---- Layer 0: fused hs|hd|res from x0; agg adds onto res (in P) ----
    hipLaunchKernelGGL((gemm_lds<float, 3, 128, false, false>), dim3(2, mtiles), blk, 0, stream,
                       x0, t_src0, t_dst0, t_res0, b_src0, b_dst0, b_res0,
                       HS, HD, P,
                       (const bf16_t*)nullptr, (const float*)nullptr, (float*)nullptr,
                       N, 256, 256);
    hipLaunchKernelGGL((gat_agg_wave<64, false, true>), dim3(ab), blk, 0, stream,
                       HS, HD, attn0, row_start, src_sorted, P, (float*)nullptr, N);

    // ---- Layer 1: fused hs|hd from P; identity residual in-place ----
    hipLaunchKernelGGL((gemm_lds<bf16_t, 2, 256, false, false>), dim3(2, mtiles), blk, 0, stream,
                       P, t_src1, t_dst1, (const bf16_t*)nullptr, b_src1, b_dst1, (const float*)nullptr,
                       HS, HD, (bf16_t*)nullptr,
                       (const bf16_t*)nullptr, (const float*)nullptr, (float*)nullptr,
                       N, 256, 256);
    hipLaunchKernelGGL((gat_agg_wave<64, false, true>), dim3(ab), blk, 0, stream,
                       HS, HD, attn1, row_start, src_sorted, P, (float*)nullptr, N);

    // ---- Layer 2: fused hs|hd (SPLIT40) + eff residual (f32 -> out); FINAL agg accumulates ----
    hipLaunchKernelGGL((gemm_lds<bf16_t, 2, 256, true, true>), dim3(2, mtiles), blk, 0, stream,
                       P, t_src2, t_dst2, (const bf16_t*)nullptr, b_src2, b_dst2, (const float*)nullptr,
                       HS, HD, (bf16_t*)nullptr,
                       t_eff, b_eff, out,
                       N, 160, 192);
    hipLaunchKernelGGL((gat_agg_wave<40, true, false>), dim3(ab), blk, 0, stream,
                       HS, HD, attn2, row_start, src_sorted, (bf16_t*)nullptr, out, N);
}

// Round 8
// 481.394 us; speedup vs baseline: 1.0862x; 1.0862x over previous
//
#include <hip/hip_runtime.h>
#include <hip/hip_bf16.h>
#include <math.h>

// N=50000, E=400000, F_IN=128, HID=64, OUT=40, H=4
#define SLOPE 0.2f

typedef unsigned short bf16_t;
typedef short bh8 __attribute__((ext_vector_type(8)));
typedef float f32x4 __attribute__((ext_vector_type(4)));

__device__ __forceinline__ float bf2f(bf16_t x) {
    return __uint_as_float((unsigned)x << 16);
}
__device__ __forceinline__ bf16_t f2bf(float v) {
    unsigned u = __float_as_uint(v);
    return (bf16_t)((u + 0x7FFFu + ((u >> 16) & 1u)) >> 16);  // RNE
}
__device__ __forceinline__ ushort2 pk_f2bf(float a, float b) {
    __hip_bfloat162 h2 = __float22bfloat162_rn(float2{a, b});  // v_cvt_pk_bf16_f32
    union { __hip_bfloat162 h; ushort2 u; } u;
    u.h = h2;
    return u.u;
}

// ---------------- CSR build (verified R2-R7) ----------------

__global__ void hist_dst(const int* __restrict__ dst, int E, int* __restrict__ deg) {
    int e = blockIdx.x * 256 + threadIdx.x;
    if (e < E) atomicAdd(&deg[dst[e]], 1);
}

__global__ void deg_chunk_sum(const int* __restrict__ deg, int n, int* __restrict__ chunk_sums) {
    __shared__ int sm[256];
    int base = blockIdx.x * 1024;
    int s = 0;
    for (int i = threadIdx.x; i < 1024; i += 256) {
        int idx = base + i;
        if (idx < n) s += deg[idx];
    }
    sm[threadIdx.x] = s;
    __syncthreads();
    for (int off = 128; off > 0; off >>= 1) {
        if (threadIdx.x < off) sm[threadIdx.x] += sm[threadIdx.x + off];
        __syncthreads();
    }
    if (threadIdx.x == 0) chunk_sums[blockIdx.x] = sm[0];
}

__global__ void scan_chunk_sums(int* __restrict__ chunk_sums, int nchunks) {
    __shared__ int sm[256];
    int t = threadIdx.x;
    if (t < nchunks) sm[t] = chunk_sums[t];
    __syncthreads();
    if (t == 0) {
        int run = 0;
        for (int i = 0; i < nchunks; i++) { int v = sm[i]; sm[i] = run; run += v; }
    }
    __syncthreads();
    if (t < nchunks) chunk_sums[t] = sm[t];
}

__global__ void scan_write(const int* __restrict__ deg, int n,
                           const int* __restrict__ chunk_sums,
                           int* __restrict__ row_start, int Etot) {
    int base = blockIdx.x * 1024;
    int t = threadIdx.x;
    int v[4];
    int tsum = 0;
#pragma unroll
    for (int j = 0; j < 4; j++) {
        int idx = base + t * 4 + j;
        v[j] = (idx < n) ? deg[idx] : 0;
        tsum += v[j];
    }
    __shared__ int sm[256];
    sm[t] = tsum;
    __syncthreads();
    for (int off = 1; off < 256; off <<= 1) {
        int x = (t >= off) ? sm[t - off] : 0;
        __syncthreads();
        sm[t] += x;
        __syncthreads();
    }
    int excl = sm[t] - tsum + chunk_sums[blockIdx.x];
#pragma unroll
    for (int j = 0; j < 4; j++) {
        int idx = base + t * 4 + j;
        if (idx < n) row_start[idx] = excl;
        excl += v[j];
    }
    if (blockIdx.x == 0 && t == 0) row_start[n] = Etot;
}

__global__ void scatter_edges(const int* __restrict__ dst, const int* __restrict__ src, int E,
                              const int* __restrict__ row_start,
                              int* __restrict__ fill, int* __restrict__ src_sorted) {
    int e = blockIdx.x * 256 + threadIdx.x;
    if (e < E) {
        int d_ = dst[e];
        int pos = row_start[d_] + atomicAdd(&fill[d_], 1);
        src_sorted[pos] = src[e];
    }
}

// ---------------- weight conversion: W[K][Nc] f32 -> Wt[Npad][K] bf16 (verified R3) ----------------

__global__ void convert_weights(
    const float* __restrict__ w0, const float* __restrict__ w1, const float* __restrict__ w2,
    const float* __restrict__ w3, const float* __restrict__ w4,
    const float* __restrict__ w5, const float* __restrict__ w6,
    const float* __restrict__ wr2, const float* __restrict__ br2,
    bf16_t* __restrict__ t0, bf16_t* __restrict__ t1, bf16_t* __restrict__ t2,
    bf16_t* __restrict__ t3, bf16_t* __restrict__ t4,
    bf16_t* __restrict__ t5, bf16_t* __restrict__ t6,
    bf16_t* __restrict__ teff, float* __restrict__ b_eff)
{
    int b = blockIdx.x, t = threadIdx.x;
    const float* W; bf16_t* T; int K, Nc, lb;
    if (b < 384) {
        int g = b / 128; lb = b - g * 128;
        W = g == 0 ? w0 : (g == 1 ? w1 : w2);
        T = g == 0 ? t0 : (g == 1 ? t1 : t2);
        K = 128; Nc = 256;
    } else if (b < 896) {
        int g = (b - 384) / 256; lb = (b - 384) - g * 256;
        W = g == 0 ? w3 : w4; T = g == 0 ? t3 : t4;
        K = 256; Nc = 256;
    } else if (b < 1280) {
        int g = (b - 896) / 192; lb = (b - 896) - g * 192;
        W = g == 0 ? w5 : w6; T = g == 0 ? t5 : t6;
        K = 256; Nc = 160;
    } else {
        lb = b - 1280;
        int idx = lb * 256 + t;          // 64*256 = 16384 elems
        int n = idx >> 8, k = idx & 255;
        float v = 0.f;
        if (n < 40)
            v = 0.25f * (wr2[(size_t)k * 160 + n] + wr2[(size_t)k * 160 + 40 + n] +
                         wr2[(size_t)k * 160 + 80 + n] + wr2[(size_t)k * 160 + 120 + n]);
        teff[idx] = f2bf(v);
        if (lb == 0 && t < 40)
            b_eff[t] = 0.25f * (br2[t] + br2[40 + t] + br2[80 + t] + br2[120 + t]);
        return;
    }
    int idx = lb * 256 + t;
    int n = idx / K, k = idx - n * K;
    float v = (n < Nc) ? W[(size_t)k * Nc + n] : 0.f;
    T[idx] = f2bf(v);
}

// ---------------- single-A-stage multi-output MFMA GEMM ----------------
// 1-D grid over 64-row m-tiles. The 64xK A-slab is staged in LDS ONCE
// (A read from HBM exactly once per layer), then the block loops over
// column-chunks of 128 (4 waves x 32 cols) reusing the staged A. Epilogue
// uses a SEPARATE LDS region (per-wave 64x38) so staging LDS is never
// clobbered -> only ONE barrier in the whole kernel. HAS_EFF: after the
// chunk loop, waves 0-1 run a folded-residual pass (Wte 64xK -> Ce f32
// [M,40], overwrite incl. bias) reusing LDS A; later FINAL agg accumulates.

template <typename TA, int NOUT, int KTOT, int NPAD, bool SPLIT40, bool HAS_EFF>
__global__ __launch_bounds__(256) void gemm_lds(
    const TA* __restrict__ A,
    const bf16_t* __restrict__ Wt0, const bf16_t* __restrict__ Wt1, const bf16_t* __restrict__ Wt2,
    const float* __restrict__ bias0, const float* __restrict__ bias1, const float* __restrict__ bias2,
    bf16_t* __restrict__ C0, bf16_t* __restrict__ C1, bf16_t* __restrict__ C2,
    const bf16_t* __restrict__ Wte, const float* __restrict__ biase, float* __restrict__ Ce,
    int M, int Nc)
{
    constexpr int LSTR = KTOT + 8;     // stage row stride (balanced banks)
    constexpr int ESTR = 38;           // epilogue row stride
    __shared__ bf16_t As[64 * LSTR];
    __shared__ bf16_t Ep[4 * 64 * ESTR];

    int tid = threadIdx.x;
    int lane = tid & 63, w = tid >> 6;
    int lm = lane & 15, lq = lane >> 4;
    int m0 = blockIdx.x * 64;

    const bf16_t* Wts[3] = {Wt0, Wt1, Wt2};
    const float* biases[3] = {bias0, bias1, bias2};
    bf16_t* Cs[3] = {C0, C1, C2};

    // ---- stage A slab (64 rows x KTOT) once ----
    if (sizeof(TA) == 4) {            // KTOT == 128, f32 input
#pragma unroll
        for (int it = 0; it < 4; it++) {
            int idx = tid + it * 256;  // 1024 chunks of 8 floats
            int r = idx >> 4, c = idx & 15;
            int gm = m0 + r; if (gm >= M) gm = M - 1;
            const float* ap = (const float*)A + (size_t)gm * KTOT + c * 8;
            float4 lo = *(const float4*)ap;
            float4 hi = *(const float4*)(ap + 4);
            ushort2 p0 = pk_f2bf(lo.x, lo.y), p1 = pk_f2bf(lo.z, lo.w);
            ushort2 p2 = pk_f2bf(hi.x, hi.y), p3 = pk_f2bf(hi.z, hi.w);
            bh8 v = { (short)p0.x, (short)p0.y, (short)p1.x, (short)p1.y,
                      (short)p2.x, (short)p2.y, (short)p3.x, (short)p3.y };
            *(bh8*)(As + r * LSTR + c * 8) = v;
        }
    } else {                           // KTOT == 256, bf16 input
#pragma unroll
        for (int it = 0; it < 8; it++) {
            int idx = tid + it * 256;  // 2048 chunks of 8 bf16
            int r = idx >> 5, c = idx & 31;
            int gm = m0 + r; if (gm >= M) gm = M - 1;
            bh8 v = *(const bh8*)((const bf16_t*)A + (size_t)gm * KTOT + c * 8);
            *(bh8*)(As + r * LSTR + c * 8) = v;
        }
    }
    __syncthreads();   // the ONLY barrier

    bf16_t* ep = Ep + w * (64 * ESTR);
    constexpr int NCHUNK = (NPAD + 127) / 128;

#pragma unroll
    for (int chunk = 0; chunk < NCHUNK; chunk++) {
        int n0 = chunk * 128 + w * 32;
        if (n0 >= NPAD) continue;      // no barriers inside -> safe

        int boff[NOUT][2];
#pragma unroll
        for (int o = 0; o < NOUT; o++)
#pragma unroll
            for (int nt = 0; nt < 2; nt++)
                boff[o][nt] = (n0 + nt * 16 + lm) * KTOT + lq * 8;

        f32x4 acc[NOUT][4][2];
#pragma unroll
        for (int o = 0; o < NOUT; o++)
#pragma unroll
            for (int i = 0; i < 4; i++)
#pragma unroll
                for (int j = 0; j < 2; j++)
                    acc[o][i][j] = (f32x4){0.f, 0.f, 0.f, 0.f};

#pragma unroll
        for (int kc = 0; kc < KTOT / 32; kc++) {
            bh8 af[4];
#pragma unroll
            for (int mt = 0; mt < 4; mt++)
                af[mt] = *(const bh8*)(As + (mt * 16 + lm) * LSTR + kc * 32 + lq * 8);
#pragma unroll
            for (int o = 0; o < NOUT; o++) {
                bh8 bf[2];
#pragma unroll
                for (int nt = 0; nt < 2; nt++)
                    bf[nt] = *(const bh8*)(Wts[o] + boff[o][nt] + kc * 32);
#pragma unroll
                for (int mt = 0; mt < 4; mt++)
#pragma unroll
                    for (int nt = 0; nt < 2; nt++)
                        acc[o][mt][nt] = __builtin_amdgcn_mfma_f32_16x16x32_bf16(af[mt], bf[nt], acc[o][mt][nt], 0, 0, 0);
            }
        }

        // ---- per-wave epilogue: private LDS tile -> full-line global stores ----
#pragma unroll
        for (int o = 0; o < NOUT; o++) {
#pragma unroll
            for (int nt = 0; nt < 2; nt++) {
                int gn = n0 + nt * 16 + lm;
                float bv = (gn < Nc) ? biases[o][gn] : 0.f;
#pragma unroll
                for (int mt = 0; mt < 4; mt++)
#pragma unroll
                    for (int r = 0; r < 4; r++)
                        ep[(mt * 16 + lq * 4 + r) * ESTR + nt * 16 + lm] = f2bf(acc[o][mt][nt][r] + bv);
            }
#pragma unroll
            for (int it = 0; it < 4; it++) {
                int row = it * 16 + (lane >> 2);
                int cc = (lane & 3) * 8;
                bh8 v = *(const bh8*)(ep + row * ESTR + cc);
                int gm = m0 + row;
                int cg = n0 + cc;
                if (gm < M && cg < Nc) {
                    size_t cb = SPLIT40 ? (size_t)(cg + 24 * (cg / 40)) : (size_t)cg;
                    size_t rs = SPLIT40 ? 256 : (size_t)Nc;
                    *(bh8*)(Cs[o] + (size_t)gm * rs + cb) = v;
                }
            }
        }
    }

    // ---- folded-residual pass (waves 0-1), reuses LDS A ----
    if (HAS_EFF && w < 2) {
        int beoff[2];
#pragma unroll
        for (int nt = 0; nt < 2; nt++)
            beoff[nt] = (w * 32 + nt * 16 + lm) * KTOT + lq * 8;
        f32x4 acc_e[4][2];
#pragma unroll
        for (int i = 0; i < 4; i++)
#pragma unroll
            for (int j = 0; j < 2; j++)
                acc_e[i][j] = (f32x4){0.f, 0.f, 0.f, 0.f};
#pragma unroll
        for (int kc = 0; kc < KTOT / 32; kc++) {
            bh8 af[4];
#pragma unroll
            for (int mt = 0; mt < 4; mt++)
                af[mt] = *(const bh8*)(As + (mt * 16 + lm) * LSTR + kc * 32 + lq * 8);
            bh8 be[2];
#pragma unroll
            for (int nt = 0; nt < 2; nt++)
                be[nt] = *(const bh8*)(Wte + beoff[nt] + kc * 32);
#pragma unroll
            for (int mt = 0; mt < 4; mt++)
#pragma unroll
                for (int nt = 0; nt < 2; nt++)
                    acc_e[mt][nt] = __builtin_amdgcn_mfma_f32_16x16x32_bf16(af[mt], be[nt], acc_e[mt][nt], 0, 0, 0);
        }
#pragma unroll
        for (int nt = 0; nt < 2; nt++) {
            int gn = w * 32 + nt * 16 + lm;
            if (gn >= 40) continue;
            float bv = biase[gn];
#pragma unroll
            for (int mt = 0; mt < 4; mt++)
#pragma unroll
                for (int r = 0; r < 4; r++) {
                    int gm = m0 + mt * 16 + lq * 4 + r;
                    if (gm < M) Ce[(size_t)gm * 40 + gn] = acc_e[mt][nt][r] + bv;
                }
        }
    }
}

// ---------------- GATv2 aggregation: one WAVE per node, 4 branchy chains (R6-verified) ----------------

__device__ __forceinline__ float edge_logit(const float h[4], const float hdf[4], const float at[4]) {
    float p = 0.f;
#pragma unroll
    for (int j = 0; j < 4; j++) {
        float q = h[j] + hdf[j];
        float lr = fmaxf(q, SLOPE * q);   // LeakyReLU, slope<1: max(q, 0.2q)
        p += lr * at[j];
    }
    p += __shfl_xor(p, 1, 64);
    p += __shfl_xor(p, 2, 64);
    p += __shfl_xor(p, 4, 64);
    p += __shfl_xor(p, 8, 64);
    return p;
}

__device__ __forceinline__ void chain_update(float logit, const float h[4],
                                             float& m, float& l, float* a) {
    if (logit > m) {
        float sc = __expf(m - logit);   // m=-inf first time -> 0
        l = l * sc + 1.f;
#pragma unroll
        for (int j = 0; j < 4; j++) a[j] = a[j] * sc + h[j];
        m = logit;
    } else {
        float p = __expf(logit - m);
        l += p;
#pragma unroll
        for (int j = 0; j < 4; j++) a[j] += p * h[j];
    }
}

template <int DVALID, bool FINAL, bool RES_INPLACE>
__global__ __launch_bounds__(256) void gat_agg_wave(
    const bf16_t* __restrict__ hs, const bf16_t* __restrict__ hd,
    const float* __restrict__ attn,
    const int* __restrict__ row_start, const int* __restrict__ src_sorted,
    bf16_t* __restrict__ P, float* __restrict__ out_final, int N)
{
    int w = threadIdx.x >> 6, l = threadIdx.x & 63;
    int n = blockIdx.x * 4 + w;
    if (n >= N) return;
    int h = l >> 4;
    int f0 = 4 * l;
    int dp = 4 * (l & 15);

    float at[4];
#pragma unroll
    for (int j = 0; j < 4; j++)
        at[j] = (dp + j < DVALID) ? attn[h * DVALID + dp + j] : 0.f;
    ushort4 hv = *(const ushort4*)(hd + (unsigned)(n * 256 + f0));
    float hdf[4] = { bf2f(hv.x), bf2f(hv.y), bf2f(hv.z), bf2f(hv.w) };

    int s = row_start[n], e = row_start[n + 1];

    float cm[4] = {-INFINITY, -INFINITY, -INFINITY, -INFINITY};
    float cl[4] = {0.f, 0.f, 0.f, 0.f};
    float ca[4][4] = {};

    int i = s;
    for (; i + 4 <= e; i += 4) {
        int sn0 = src_sorted[i], sn1 = src_sorted[i + 1];
        int sn2 = src_sorted[i + 2], sn3 = src_sorted[i + 3];
        ushort4 r0 = *(const ushort4*)(hs + (unsigned)(sn0 * 256 + f0));
        ushort4 r1 = *(const ushort4*)(hs + (unsigned)(sn1 * 256 + f0));
        ushort4 r2 = *(const ushort4*)(hs + (unsigned)(sn2 * 256 + f0));
        ushort4 r3 = *(const ushort4*)(hs + (unsigned)(sn3 * 256 + f0));
        float h0[4] = { bf2f(r0.x), bf2f(r0.y), bf2f(r0.z), bf2f(r0.w) };
        float h1[4] = { bf2f(r1.x), bf2f(r1.y), bf2f(r1.z), bf2f(r1.w) };
        float h2[4] = { bf2f(r2.x), bf2f(r2.y), bf2f(r2.z), bf2f(r2.w) };
        float h3[4] = { bf2f(r3.x), bf2f(r3.y), bf2f(r3.z), bf2f(r3.w) };
        float p0 = edge_logit(h0, hdf, at);
        float p1 = edge_logit(h1, hdf, at);
        float p2 = edge_logit(h2, hdf, at);
        float p3 = edge_logit(h3, hdf, at);
        chain_update(p0, h0, cm[0], cl[0], ca[0]);
        chain_update(p1, h1, cm[1], cl[1], ca[1]);
        chain_update(p2, h2, cm[2], cl[2], ca[2]);
        chain_update(p3, h3, cm[3], cl[3], ca[3]);
    }
    for (; i < e; i++) {
        int sn0 = src_sorted[i];
        ushort4 r0 = *(const ushort4*)(hs + (unsigned)(sn0 * 256 + f0));
        float h0[4] = { bf2f(r0.x), bf2f(r0.y), bf2f(r0.z), bf2f(r0.w) };
        float p0 = edge_logit(h0, hdf, at);
        chain_update(p0, h0, cm[0], cl[0], ca[0]);
    }

    float v[4] = {0.f, 0.f, 0.f, 0.f};
    if (e > s) {
        float M = fmaxf(fmaxf(cm[0], cm[1]), fmaxf(cm[2], cm[3]));
        float L = 0.f;
#pragma unroll
        for (int c = 0; c < 4; c++) {
            float sc = __expf(cm[c] - M);   // empty chain: exp(-inf)=0
            L += sc * cl[c];
#pragma unroll
            for (int j = 0; j < 4; j++) v[j] += sc * ca[c][j];
        }
        float inv = 1.f / L;
#pragma unroll
        for (int j = 0; j < 4; j++) v[j] *= inv;
    }

    if (FINAL) {
#pragma unroll
        for (int j = 0; j < 4; j++) {
            v[j] += __shfl_xor(v[j], 16, 64);
            v[j] += __shfl_xor(v[j], 32, 64);
        }
        if (l < DVALID / 4) {
            float4* op = (float4*)(out_final + (unsigned)(n * DVALID + 4 * l));
            float4 cur = *op;
            cur.x += 0.25f * v[0]; cur.y += 0.25f * v[1];
            cur.z += 0.25f * v[2]; cur.w += 0.25f * v[3];
            *op = cur;
        }
    } else {
        unsigned oi = (unsigned)(n * 256 + f0);
        if (RES_INPLACE) {
            ushort4 pv = *(const ushort4*)(P + oi);
            v[0] += bf2f(pv.x); v[1] += bf2f(pv.y);
            v[2] += bf2f(pv.z); v[3] += bf2f(pv.w);
        }
        ushort4 ov = { f2bf(v[0]), f2bf(v[1]), f2bf(v[2]), f2bf(v[3]) };
        *(ushort4*)(P + oi) = ov;
    }
}

// ---------------- launch ----------------

extern "C" void kernel_launch(void* const* d_in, const int* in_sizes, int n_in,
                              void* d_out, int out_size, void* d_ws, size_t ws_size,
                              hipStream_t stream) {
    const float* x0    = (const float*)d_in[0];
    const int*   src   = (const int*)d_in[1];
    const int*   dst   = (const int*)d_in[2];
    const float* w_src0 = (const float*)d_in[3];  const float* b_src0 = (const float*)d_in[4];
    const float* w_dst0 = (const float*)d_in[5];  const float* b_dst0 = (const float*)d_in[6];
    const float* attn0  = (const float*)d_in[7];
    const float* w_res0 = (const float*)d_in[8];  const float* b_res0 = (const float*)d_in[9];
    const float* w_src1 = (const float*)d_in[10]; const float* b_src1 = (const float*)d_in[11];
    const float* w_dst1 = (const float*)d_in[12]; const float* b_dst1 = (const float*)d_in[13];
    const float* attn1  = (const float*)d_in[14];
    const float* w_src2 = (const float*)d_in[15]; const float* b_src2 = (const float*)d_in[16];
    const float* w_dst2 = (const float*)d_in[17]; const float* b_dst2 = (const float*)d_in[18];
    const float* attn2  = (const float*)d_in[19];
    const float* w_res2 = (const float*)d_in[20]; const float* b_res2 = (const float*)d_in[21];

    const int N = in_sizes[0] / 128;   // 50000
    const int E = in_sizes[1];         // 400000
    float* out = (float*)d_out;
    (void)n_in; (void)out_size; (void)ws_size;

    // ---- workspace (~80 MB) ----
    char* ws = (char*)d_ws;
    size_t off = 0;
    auto alloc = [&](size_t bytes) {
        void* q = ws + off;
        off = (off + bytes + 255) & ~(size_t)255;
        return q;
    };
    int* deg        = (int*)alloc((size_t)2 * N * 4);
    int* fill       = deg + N;
    int* row_start  = (int*)alloc((size_t)(N + 1) * 4);
    int* chunk_sums = (int*)alloc(256 * 4);
    int* src_sorted = (int*)alloc((size_t)E * 4);
    bf16_t* t_src0 = (bf16_t*)alloc(256 * 128 * 2);
    bf16_t* t_dst0 = (bf16_t*)alloc(256 * 128 * 2);
    bf16_t* t_res0 = (bf16_t*)alloc(256 * 128 * 2);
    bf16_t* t_src1 = (bf16_t*)alloc(256 * 256 * 2);
    bf16_t* t_dst1 = (bf16_t*)alloc(256 * 256 * 2);
    bf16_t* t_src2 = (bf16_t*)alloc(192 * 256 * 2);
    bf16_t* t_dst2 = (bf16_t*)alloc(192 * 256 * 2);
    bf16_t* t_eff  = (bf16_t*)alloc(64 * 256 * 2);
    float*  b_eff  = (float*)alloc(64 * 4);
    const size_t elems = (size_t)N * 256;
    bf16_t* P  = (bf16_t*)alloc(elems * 2);
    bf16_t* HS = (bf16_t*)alloc(elems * 2);
    bf16_t* HD = (bf16_t*)alloc(elems * 2);

    // ---- CSR build + weight conversion ----
    hipMemsetAsync(deg, 0, (size_t)2 * N * 4, stream);
    int eblocks = (E + 255) / 256;
    int nchunks = (N + 1023) / 1024;
    hipLaunchKernelGGL(hist_dst, dim3(eblocks), dim3(256), 0, stream, dst, E, deg);
    hipLaunchKernelGGL(convert_weights, dim3(1344), dim3(256), 0, stream,
                       w_src0, w_dst0, w_res0, w_src1, w_dst1, w_src2, w_dst2, w_res2, b_res2,
                       t_src0, t_dst0, t_res0, t_src1, t_dst1, t_src2, t_dst2, t_eff, b_eff);
    hipLaunchKernelGGL(deg_chunk_sum, dim3(nchunks), dim3(256), 0, stream, deg, N, chunk_sums);
    hipLaunchKernelGGL(scan_chunk_sums, dim3(1), dim3(256), 0, stream, chunk_sums, nchunks);
    hipLaunchKernelGGL(scan_write, dim3(nchunks), dim3(256), 0, stream, deg, N, chunk_sums, row_start, E);
    hipLaunchKernelGGL(scatter_edges, dim3(eblocks), dim3(256), 0, stream, dst, src, E, row_start, fill, src_sorted);

    dim3 blk(256);
    int mtiles = (N + 63) / 64;        // 782
    int ab = (N + 3) / 4;              // 12500 (wave-per-node agg)

    // ---- Layer 0: fused hs|hd|res from x0; agg adds onto res (in P) ----
    hipLaunchKernelGGL((gemm_lds<float, 3, 128, 256, false, false>), dim3(mtiles), blk, 0, stream,
                       x0, t_src0, t_dst0, t_res0, b_src0, b_dst0, b_res0,
                       HS, HD, P,
                       (const bf16_t*)nullptr, (const float*)nullptr, (float*)nullptr,
                       N, 256);
    hipLaunchKernelGGL((gat_agg_wave<64, false, true>), dim3(ab), blk, 0, stream,
                       HS, HD, attn0, row_start, src_sorted, P, (float*)nullptr, N);

    // ---- Layer 1: fused hs|hd from P; identity residual in-place ----
    hipLaunchKernelGGL((gemm_lds<bf16_t, 2, 256, 256, false, false>), dim3(mtiles), blk, 0, stream,
                       P, t_src1, t_dst1, (const bf16_t*)nullptr, b_src1, b_dst1, (const float*)nullptr,
                       HS, HD, (bf16_t*)nullptr,
                       (const bf16_t*)nullptr, (const float*)nullptr, (float*)nullptr,
                       N, 256);
    hipLaunchKernelGGL((gat_agg_wave<64, false, true>), dim3(ab), blk, 0, stream,
                       HS, HD, attn1, row_start, src_sorted, P, (float*)nullptr, N);

    // ---- Layer 2: fused hs|hd (SPLIT40) + eff residual (f32 -> out); FINAL agg accumulates ----
    hipLaunchKernelGGL((gemm_lds<bf16_t, 2, 256, 192, true, true>), dim3(mtiles), blk, 0, stream,
                       P, t_src2, t_dst2, (const bf16_t*)nullptr, b_src2, b_dst2, (const float*)nullptr,
                       HS, HD, (bf16_t*)nullptr,
                       t_eff, b_eff, out,
                       N, 160);
    hipLaunchKernelGGL((gat_agg_wave<40, true, false>), dim3(ab), blk, 0, stream,
                       HS, HD, attn2, row_start, src_sorted, (bf16_t*)nullptr, out, N);
}

// Round 9
// 455.224 us; speedup vs baseline: 1.1487x; 1.0575x over previous
//
#include <hip/hip_runtime.h>
#include <hip/hip_bf16.h>
#include <math.h>

// N=50000, E=400000, F_IN=128, HID=64, OUT=40, H=4
#define SLOPE 0.2f

typedef unsigned short bf16_t;
typedef short bh8 __attribute__((ext_vector_type(8)));
typedef unsigned short us8 __attribute__((ext_vector_type(8)));
typedef float f32x4 __attribute__((ext_vector_type(4)));

__device__ __forceinline__ float bf2f(bf16_t x) {
    return __uint_as_float((unsigned)x << 16);
}
__device__ __forceinline__ bf16_t f2bf(float v) {
    unsigned u = __float_as_uint(v);
    return (bf16_t)((u + 0x7FFFu + ((u >> 16) & 1u)) >> 16);  // RNE
}
__device__ __forceinline__ ushort2 pk_f2bf(float a, float b) {
    __hip_bfloat162 h2 = __float22bfloat162_rn(float2{a, b});  // v_cvt_pk_bf16_f32
    union { __hip_bfloat162 h; ushort2 u; } u;
    u.h = h2;
    return u.u;
}

// ---------------- CSR build (verified R2-R8) ----------------

__global__ void hist_dst(const int* __restrict__ dst, int E, int* __restrict__ deg) {
    int e = blockIdx.x * 256 + threadIdx.x;
    if (e < E) atomicAdd(&deg[dst[e]], 1);
}

__global__ void deg_chunk_sum(const int* __restrict__ deg, int n, int* __restrict__ chunk_sums) {
    __shared__ int sm[256];
    int base = blockIdx.x * 1024;
    int s = 0;
    for (int i = threadIdx.x; i < 1024; i += 256) {
        int idx = base + i;
        if (idx < n) s += deg[idx];
    }
    sm[threadIdx.x] = s;
    __syncthreads();
    for (int off = 128; off > 0; off >>= 1) {
        if (threadIdx.x < off) sm[threadIdx.x] += sm[threadIdx.x + off];
        __syncthreads();
    }
    if (threadIdx.x == 0) chunk_sums[blockIdx.x] = sm[0];
}

__global__ void scan_chunk_sums(int* __restrict__ chunk_sums, int nchunks) {
    __shared__ int sm[256];
    int t = threadIdx.x;
    if (t < nchunks) sm[t] = chunk_sums[t];
    __syncthreads();
    if (t == 0) {
        int run = 0;
        for (int i = 0; i < nchunks; i++) { int v = sm[i]; sm[i] = run; run += v; }
    }
    __syncthreads();
    if (t < nchunks) chunk_sums[t] = sm[t];
}

__global__ void scan_write(const int* __restrict__ deg, int n,
                           const int* __restrict__ chunk_sums,
                           int* __restrict__ row_start, int Etot) {
    int base = blockIdx.x * 1024;
    int t = threadIdx.x;
    int v[4];
    int tsum = 0;
#pragma unroll
    for (int j = 0; j < 4; j++) {
        int idx = base + t * 4 + j;
        v[j] = (idx < n) ? deg[idx] : 0;
        tsum += v[j];
    }
    __shared__ int sm[256];
    sm[t] = tsum;
    __syncthreads();
    for (int off = 1; off < 256; off <<= 1) {
        int x = (t >= off) ? sm[t - off] : 0;
        __syncthreads();
        sm[t] += x;
        __syncthreads();
    }
    int excl = sm[t] - tsum + chunk_sums[blockIdx.x];
#pragma unroll
    for (int j = 0; j < 4; j++) {
        int idx = base + t * 4 + j;
        if (idx < n) row_start[idx] = excl;
        excl += v[j];
    }
    if (blockIdx.x == 0 && t == 0) row_start[n] = Etot;
}

__global__ void scatter_edges(const int* __restrict__ dst, const int* __restrict__ src, int E,
                              const int* __restrict__ row_start,
                              int* __restrict__ fill, int* __restrict__ src_sorted) {
    int e = blockIdx.x * 256 + threadIdx.x;
    if (e < E) {
        int d_ = dst[e];
        int pos = row_start[d_] + atomicAdd(&fill[d_], 1);
        src_sorted[pos] = src[e];
    }
}

// ---------------- weight conversion (verified R3) ----------------

__global__ void convert_weights(
    const float* __restrict__ w0, const float* __restrict__ w1, const float* __restrict__ w2,
    const float* __restrict__ w3, const float* __restrict__ w4,
    const float* __restrict__ w5, const float* __restrict__ w6,
    const float* __restrict__ wr2, const float* __restrict__ br2,
    bf16_t* __restrict__ t0, bf16_t* __restrict__ t1, bf16_t* __restrict__ t2,
    bf16_t* __restrict__ t3, bf16_t* __restrict__ t4,
    bf16_t* __restrict__ t5, bf16_t* __restrict__ t6,
    bf16_t* __restrict__ teff, float* __restrict__ b_eff)
{
    int b = blockIdx.x, t = threadIdx.x;
    const float* W; bf16_t* T; int K, Nc, lb;
    if (b < 384) {
        int g = b / 128; lb = b - g * 128;
        W = g == 0 ? w0 : (g == 1 ? w1 : w2);
        T = g == 0 ? t0 : (g == 1 ? t1 : t2);
        K = 128; Nc = 256;
    } else if (b < 896) {
        int g = (b - 384) / 256; lb = (b - 384) - g * 256;
        W = g == 0 ? w3 : w4; T = g == 0 ? t3 : t4;
        K = 256; Nc = 256;
    } else if (b < 1280) {
        int g = (b - 896) / 192; lb = (b - 896) - g * 192;
        W = g == 0 ? w5 : w6; T = g == 0 ? t5 : t6;
        K = 256; Nc = 160;
    } else {
        lb = b - 1280;
        int idx = lb * 256 + t;          // 64*256 = 16384 elems
        int n = idx >> 8, k = idx & 255;
        float v = 0.f;
        if (n < 40)
            v = 0.25f * (wr2[(size_t)k * 160 + n] + wr2[(size_t)k * 160 + 40 + n] +
                         wr2[(size_t)k * 160 + 80 + n] + wr2[(size_t)k * 160 + 120 + n]);
        teff[idx] = f2bf(v);
        if (lb == 0 && t < 40)
            b_eff[t] = 0.25f * (br2[t] + br2[40 + t] + br2[80 + t] + br2[120 + t]);
        return;
    }
    int idx = lb * 256 + t;
    int n = idx / K, k = idx - n * K;
    float v = (n < Nc) ? W[(size_t)k * Nc + n] : 0.f;
    T[idx] = f2bf(v);
}

// ---------------- single-A-stage multi-output MFMA GEMM (R8-verified) ----------------

template <typename TA, int NOUT, int KTOT, int NPAD, bool SPLIT40, bool HAS_EFF>
__global__ __launch_bounds__(256) void gemm_lds(
    const TA* __restrict__ A,
    const bf16_t* __restrict__ Wt0, const bf16_t* __restrict__ Wt1, const bf16_t* __restrict__ Wt2,
    const float* __restrict__ bias0, const float* __restrict__ bias1, const float* __restrict__ bias2,
    bf16_t* __restrict__ C0, bf16_t* __restrict__ C1, bf16_t* __restrict__ C2,
    const bf16_t* __restrict__ Wte, const float* __restrict__ biase, float* __restrict__ Ce,
    int M, int Nc)
{
    constexpr int LSTR = KTOT + 8;     // stage row stride (balanced banks)
    constexpr int ESTR = 38;           // epilogue row stride
    __shared__ bf16_t As[64 * LSTR];
    __shared__ bf16_t Ep[4 * 64 * ESTR];

    int tid = threadIdx.x;
    int lane = tid & 63, w = tid >> 6;
    int lm = lane & 15, lq = lane >> 4;
    int m0 = blockIdx.x * 64;

    const bf16_t* Wts[3] = {Wt0, Wt1, Wt2};
    const float* biases[3] = {bias0, bias1, bias2};
    bf16_t* Cs[3] = {C0, C1, C2};

    // ---- stage A slab (64 rows x KTOT) once ----
    if (sizeof(TA) == 4) {            // KTOT == 128, f32 input
#pragma unroll
        for (int it = 0; it < 4; it++) {
            int idx = tid + it * 256;  // 1024 chunks of 8 floats
            int r = idx >> 4, c = idx & 15;
            int gm = m0 + r; if (gm >= M) gm = M - 1;
            const float* ap = (const float*)A + (size_t)gm * KTOT + c * 8;
            float4 lo = *(const float4*)ap;
            float4 hi = *(const float4*)(ap + 4);
            ushort2 p0 = pk_f2bf(lo.x, lo.y), p1 = pk_f2bf(lo.z, lo.w);
            ushort2 p2 = pk_f2bf(hi.x, hi.y), p3 = pk_f2bf(hi.z, hi.w);
            bh8 v = { (short)p0.x, (short)p0.y, (short)p1.x, (short)p1.y,
                      (short)p2.x, (short)p2.y, (short)p3.x, (short)p3.y };
            *(bh8*)(As + r * LSTR + c * 8) = v;
        }
    } else {                           // KTOT == 256, bf16 input
#pragma unroll
        for (int it = 0; it < 8; it++) {
            int idx = tid + it * 256;  // 2048 chunks of 8 bf16
            int r = idx >> 5, c = idx & 31;
            int gm = m0 + r; if (gm >= M) gm = M - 1;
            bh8 v = *(const bh8*)((const bf16_t*)A + (size_t)gm * KTOT + c * 8);
            *(bh8*)(As + r * LSTR + c * 8) = v;
        }
    }
    __syncthreads();   // the ONLY barrier

    bf16_t* ep = Ep + w * (64 * ESTR);
    constexpr int NCHUNK = (NPAD + 127) / 128;

#pragma unroll
    for (int chunk = 0; chunk < NCHUNK; chunk++) {
        int n0 = chunk * 128 + w * 32;
        if (n0 >= NPAD) continue;      // no barriers inside -> safe

        int boff[NOUT][2];
#pragma unroll
        for (int o = 0; o < NOUT; o++)
#pragma unroll
            for (int nt = 0; nt < 2; nt++)
                boff[o][nt] = (n0 + nt * 16 + lm) * KTOT + lq * 8;

        f32x4 acc[NOUT][4][2];
#pragma unroll
        for (int o = 0; o < NOUT; o++)
#pragma unroll
            for (int i = 0; i < 4; i++)
#pragma unroll
                for (int j = 0; j < 2; j++)
                    acc[o][i][j] = (f32x4){0.f, 0.f, 0.f, 0.f};

#pragma unroll
        for (int kc = 0; kc < KTOT / 32; kc++) {
            bh8 af[4];
#pragma unroll
            for (int mt = 0; mt < 4; mt++)
                af[mt] = *(const bh8*)(As + (mt * 16 + lm) * LSTR + kc * 32 + lq * 8);
#pragma unroll
            for (int o = 0; o < NOUT; o++) {
                bh8 bf[2];
#pragma unroll
                for (int nt = 0; nt < 2; nt++)
                    bf[nt] = *(const bh8*)(Wts[o] + boff[o][nt] + kc * 32);
#pragma unroll
                for (int mt = 0; mt < 4; mt++)
#pragma unroll
                    for (int nt = 0; nt < 2; nt++)
                        acc[o][mt][nt] = __builtin_amdgcn_mfma_f32_16x16x32_bf16(af[mt], bf[nt], acc[o][mt][nt], 0, 0, 0);
            }
        }

        // ---- per-wave epilogue: private LDS tile -> full-line global stores ----
#pragma unroll
        for (int o = 0; o < NOUT; o++) {
#pragma unroll
            for (int nt = 0; nt < 2; nt++) {
                int gn = n0 + nt * 16 + lm;
                float bv = (gn < Nc) ? biases[o][gn] : 0.f;
#pragma unroll
                for (int mt = 0; mt < 4; mt++)
#pragma unroll
                    for (int r = 0; r < 4; r++)
                        ep[(mt * 16 + lq * 4 + r) * ESTR + nt * 16 + lm] = f2bf(acc[o][mt][nt][r] + bv);
            }
#pragma unroll
            for (int it = 0; it < 4; it++) {
                int row = it * 16 + (lane >> 2);
                int cc = (lane & 3) * 8;
                bh8 v = *(const bh8*)(ep + row * ESTR + cc);
                int gm = m0 + row;
                int cg = n0 + cc;
                if (gm < M && cg < Nc) {
                    size_t cb = SPLIT40 ? (size_t)(cg + 24 * (cg / 40)) : (size_t)cg;
                    size_t rs = SPLIT40 ? 256 : (size_t)Nc;
                    *(bh8*)(Cs[o] + (size_t)gm * rs + cb) = v;
                }
            }
        }
    }

    // ---- folded-residual pass (waves 0-1), reuses LDS A ----
    if (HAS_EFF && w < 2) {
        int beoff[2];
#pragma unroll
        for (int nt = 0; nt < 2; nt++)
            beoff[nt] = (w * 32 + nt * 16 + lm) * KTOT + lq * 8;
        f32x4 acc_e[4][2];
#pragma unroll
        for (int i = 0; i < 4; i++)
#pragma unroll
            for (int j = 0; j < 2; j++)
                acc_e[i][j] = (f32x4){0.f, 0.f, 0.f, 0.f};
#pragma unroll
        for (int kc = 0; kc < KTOT / 32; kc++) {
            bh8 af[4];
#pragma unroll
            for (int mt = 0; mt < 4; mt++)
                af[mt] = *(const bh8*)(As + (mt * 16 + lm) * LSTR + kc * 32 + lq * 8);
            bh8 be[2];
#pragma unroll
            for (int nt = 0; nt < 2; nt++)
                be[nt] = *(const bh8*)(Wte + beoff[nt] + kc * 32);
#pragma unroll
            for (int mt = 0; mt < 4; mt++)
#pragma unroll
                for (int nt = 0; nt < 2; nt++)
                    acc_e[mt][nt] = __builtin_amdgcn_mfma_f32_16x16x32_bf16(af[mt], be[nt], acc_e[mt][nt], 0, 0, 0);
        }
#pragma unroll
        for (int nt = 0; nt < 2; nt++) {
            int gn = w * 32 + nt * 16 + lm;
            if (gn >= 40) continue;
            float bv = biase[gn];
#pragma unroll
            for (int mt = 0; mt < 4; mt++)
#pragma unroll
                for (int r = 0; r < 4; r++) {
                    int gm = m0 + mt * 16 + lq * 4 + r;
                    if (gm < M) Ce[(size_t)gm * 40 + gn] = acc_e[mt][nt][r] + bv;
                }
        }
    }
}

// ---------------- GATv2 aggregation: HALF-WAVE per node, 4 branchy chains ----------------
// 32 lanes per node, 8 features/lane (one 16B ushort8 load = full 512B row per
// edge per half). Head = 8-lane group; logit reduce = 3 shfls (xor 1,2,4 —
// intra-half, exec-safe). 2 nodes/wave -> 2 edges per wave-inst, 8 gathers in
// flight. Buffers stride 256 (head stride 64; pad cols attn=0).

__device__ __forceinline__ void chain_update8(float logit, const float h[8],
                                              float& m, float& l, float* a) {
    if (logit > m) {
        float sc = __expf(m - logit);   // m=-inf first time -> 0
        l = l * sc + 1.f;
#pragma unroll
        for (int j = 0; j < 8; j++) a[j] = a[j] * sc + h[j];
        m = logit;
    } else {
        float p = __expf(logit - m);
        l += p;
#pragma unroll
        for (int j = 0; j < 8; j++) a[j] += p * h[j];
    }
}

__device__ __forceinline__ float edge_logit8(const float h[8], const float hdf[8], const float at[8]) {
    float p = 0.f;
#pragma unroll
    for (int j = 0; j < 8; j++) {
        float q = h[j] + hdf[j];
        float lr = fmaxf(q, SLOPE * q);
        p += lr * at[j];
    }
    p += __shfl_xor(p, 1, 64);
    p += __shfl_xor(p, 2, 64);
    p += __shfl_xor(p, 4, 64);
    return p;
}

__device__ __forceinline__ void us8_to_f(const us8 v, float* h) {
#pragma unroll
    for (int j = 0; j < 8; j++) h[j] = bf2f(v[j]);
}

template <int DVALID, bool FINAL, bool RES_INPLACE>
__global__ __launch_bounds__(256) void gat_agg_half(
    const bf16_t* __restrict__ hs, const bf16_t* __restrict__ hd,
    const float* __restrict__ attn,
    const int* __restrict__ row_start, const int* __restrict__ src_sorted,
    bf16_t* __restrict__ P, float* __restrict__ out_final, int N)
{
    int w = threadIdx.x >> 6, lane = threadIdx.x & 63;
    int half = lane >> 5, hl = lane & 31;
    int n = blockIdx.x * 8 + w * 2 + half;
    if (n >= N) return;
    int f0 = hl * 8;          // padded feature base
    int h = hl >> 3;          // head
    int dp = (hl & 7) * 8;    // d within head (padded)

    float at[8], hdf[8];
#pragma unroll
    for (int j = 0; j < 8; j++)
        at[j] = (dp + j < DVALID) ? attn[h * DVALID + dp + j] : 0.f;
    us8 hv = *(const us8*)(hd + (unsigned)(n * 256 + f0));
    us8_to_f(hv, hdf);

    int s = row_start[n], e = row_start[n + 1];

    float cm[4] = {-INFINITY, -INFINITY, -INFINITY, -INFINITY};
    float cl[4] = {0.f, 0.f, 0.f, 0.f};
    float ca[4][8] = {};

    int i = s;
    for (; i + 4 <= e; i += 4) {
        int sn0 = src_sorted[i], sn1 = src_sorted[i + 1];
        int sn2 = src_sorted[i + 2], sn3 = src_sorted[i + 3];
        us8 r0 = *(const us8*)(hs + (unsigned)(sn0 * 256 + f0));
        us8 r1 = *(const us8*)(hs + (unsigned)(sn1 * 256 + f0));
        us8 r2 = *(const us8*)(hs + (unsigned)(sn2 * 256 + f0));
        us8 r3 = *(const us8*)(hs + (unsigned)(sn3 * 256 + f0));
        float h0[8], h1[8], h2[8], h3[8];
        us8_to_f(r0, h0); us8_to_f(r1, h1); us8_to_f(r2, h2); us8_to_f(r3, h3);
        float p0 = edge_logit8(h0, hdf, at);
        float p1 = edge_logit8(h1, hdf, at);
        float p2 = edge_logit8(h2, hdf, at);
        float p3 = edge_logit8(h3, hdf, at);
        chain_update8(p0, h0, cm[0], cl[0], ca[0]);
        chain_update8(p1, h1, cm[1], cl[1], ca[1]);
        chain_update8(p2, h2, cm[2], cl[2], ca[2]);
        chain_update8(p3, h3, cm[3], cl[3], ca[3]);
    }
    for (; i < e; i++) {
        int sn0 = src_sorted[i];
        us8 r0 = *(const us8*)(hs + (unsigned)(sn0 * 256 + f0));
        float h0[8];
        us8_to_f(r0, h0);
        float p0 = edge_logit8(h0, hdf, at);
        chain_update8(p0, h0, cm[0], cl[0], ca[0]);
    }

    float v[8] = {};
    if (e > s) {
        float M = fmaxf(fmaxf(cm[0], cm[1]), fmaxf(cm[2], cm[3]));
        float L = 0.f;
#pragma unroll
        for (int c = 0; c < 4; c++) {
            float sc = __expf(cm[c] - M);   // empty chain: exp(-inf)=0
            L += sc * cl[c];
#pragma unroll
            for (int j = 0; j < 8; j++) v[j] += sc * ca[c][j];
        }
        float inv = 1.f / L;
#pragma unroll
        for (int j = 0; j < 8; j++) v[j] *= inv;
    }

    if (FINAL) {
        // head-sum across the 4 heads: lanes hl, hl^8, hl^16, hl^24 (intra-half)
#pragma unroll
        for (int j = 0; j < 8; j++) {
            v[j] += __shfl_xor(v[j], 8, 64);
            v[j] += __shfl_xor(v[j], 16, 64);
        }
        if (hl < DVALID / 8 + 1 && h == 0 && dp < DVALID) {
            float* op = out_final + (unsigned)(n * DVALID + dp);
            float4 c0 = *(float4*)op;
            float4 c1 = *(float4*)(op + 4);
            c0.x += 0.25f * v[0]; c0.y += 0.25f * v[1];
            c0.z += 0.25f * v[2]; c0.w += 0.25f * v[3];
            c1.x += 0.25f * v[4]; c1.y += 0.25f * v[5];
            c1.z += 0.25f * v[6]; c1.w += 0.25f * v[7];
            *(float4*)op = c0;
            *(float4*)(op + 4) = c1;
        }
    } else {
        unsigned oi = (unsigned)(n * 256 + f0);
        if (RES_INPLACE) {
            us8 pv = *(const us8*)(P + oi);
#pragma unroll
            for (int j = 0; j < 8; j++) v[j] += bf2f(pv[j]);
        }
        us8 ov;
#pragma unroll
        for (int j = 0; j < 8; j++) ov[j] = f2bf(v[j]);
        *(us8*)(P + oi) = ov;
    }
}

// ---------------- launch ----------------

extern "C" void kernel_launch(void* const* d_in, const int* in_sizes, int n_in,
                              void* d_out, int out_size, void* d_ws, size_t ws_size,
                              hipStream_t stream) {
    const float* x0    = (const float*)d_in[0];
    const int*   src   = (const int*)d_in[1];
    const int*   dst   = (const int*)d_in[2];
    const float* w_src0 = (const float*)d_in[3];  const float* b_src0 = (const float*)d_in[4];
    const float* w_dst0 = (const float*)d_in[5];  const float* b_dst0 = (const float*)d_in[6];
    const float* attn0  = (const float*)d_in[7];
    const float* w_res0 = (const float*)d_in[8];  const float* b_res0 = (const float*)d_in[9];
    const float* w_src1 = (const float*)d_in[10]; const float* b_src1 = (const float*)d_in[11];
    const float* w_dst1 = (const float*)d_in[12]; const float* b_dst1 = (const float*)d_in[13];
    const float* attn1  = (const float*)d_in[14];
    const float* w_src2 = (const float*)d_in[15]; const float* b_src2 = (const float*)d_in[16];
    const float* w_dst2 = (const float*)d_in[17]; const float* b_dst2 = (const float*)d_in[18];
    const float* attn2  = (const float*)d_in[19];
    const float* w_res2 = (const float*)d_in[20]; const float* b_res2 = (const float*)d_in[21];

    const int N = in_sizes[0] / 128;   // 50000
    const int E = in_sizes[1];         // 400000
    float* out = (float*)d_out;
    (void)n_in; (void)out_size; (void)ws_size;

    // ---- workspace (~80 MB) ----
    char* ws = (char*)d_ws;
    size_t off = 0;
    auto alloc = [&](size_t bytes) {
        void* q = ws + off;
        off = (off + bytes + 255) & ~(size_t)255;
        return q;
    };
    int* deg        = (int*)alloc((size_t)2 * N * 4);
    int* fill       = deg + N;
    int* row_start  = (int*)alloc((size_t)(N + 1) * 4);
    int* chunk_sums = (int*)alloc(256 * 4);
    int* src_sorted = (int*)alloc((size_t)E * 4);
    bf16_t* t_src0 = (bf16_t*)alloc(256 * 128 * 2);
    bf16_t* t_dst0 = (bf16_t*)alloc(256 * 128 * 2);
    bf16_t* t_res0 = (bf16_t*)alloc(256 * 128 * 2);
    bf16_t* t_src1 = (bf16_t*)alloc(256 * 256 * 2);
    bf16_t* t_dst1 = (bf16_t*)alloc(256 * 256 * 2);
    bf16_t* t_src2 = (bf16_t*)alloc(192 * 256 * 2);
    bf16_t* t_dst2 = (bf16_t*)alloc(192 * 256 * 2);
    bf16_t* t_eff  = (bf16_t*)alloc(64 * 256 * 2);
    float*  b_eff  = (float*)alloc(64 * 4);
    const size_t elems = (size_t)N * 256;
    bf16_t* P  = (bf16_t*)alloc(elems * 2);
    bf16_t* HS = (bf16_t*)alloc(elems * 2);
    bf16_t* HD = (bf16_t*)alloc(elems * 2);

    // ---- CSR build + weight conversion ----
    hipMemsetAsync(deg, 0, (size_t)2 * N * 4, stream);
    int eblocks = (E + 255) / 256;
    int nchunks = (N + 1023) / 1024;
    hipLaunchKernelGGL(hist_dst, dim3(eblocks), dim3(256), 0, stream, dst, E, deg);
    hipLaunchKernelGGL(convert_weights, dim3(1344), dim3(256), 0, stream,
                       w_src0, w_dst0, w_res0, w_src1, w_dst1, w_src2, w_dst2, w_res2, b_res2,
                       t_src0, t_dst0, t_res0, t_src1, t_dst1, t_src2, t_dst2, t_eff, b_eff);
    hipLaunchKernelGGL(deg_chunk_sum, dim3(nchunks), dim3(256), 0, stream, deg, N, chunk_sums);
    hipLaunchKernelGGL(scan_chunk_sums, dim3(1), dim3(256), 0, stream, chunk_sums, nchunks);
    hipLaunchKernelGGL(scan_write, dim3(nchunks), dim3(256), 0, stream, deg, N, chunk_sums, row_start, E);
    hipLaunchKernelGGL(scatter_edges, dim3(eblocks), dim3(256), 0, stream, dst, src, E, row_start, fill, src_sorted);

    dim3 blk(256);
    int mtiles = (N + 63) / 64;        // 782
    int ab = (N + 7) / 8;              // 6250 (half-wave-per-node agg)

    // ---- Layer 0: fused hs|hd|res from x0; agg adds onto res (in P) ----
    hipLaunchKernelGGL((gemm_lds<float, 3, 128, 256, false, false>), dim3(mtiles), blk, 0, stream,
                       x0, t_src0, t_dst0, t_res0, b_src0, b_dst0, b_res0,
                       HS, HD, P,
                       (const bf16_t*)nullptr, (const float*)nullptr, (float*)nullptr,
                       N, 256);
    hipLaunchKernelGGL((gat_agg_half<64, false, true>), dim3(ab), blk, 0, stream,
                       HS, HD, attn0, row_start, src_sorted, P, (float*)nullptr, N);

    // ---- Layer 1: fused hs|hd from P; identity residual in-place ----
    hipLaunchKernelGGL((gemm_lds<bf16_t, 2, 256, 256, false, false>), dim3(mtiles), blk, 0, stream,
                       P, t_src1, t_dst1, (const bf16_t*)nullptr, b_src1, b_dst1, (const float*)nullptr,
                       HS, HD, (bf16_t*)nullptr,
                       (const bf16_t*)nullptr, (const float*)nullptr, (float*)nullptr,
                       N, 256);
    hipLaunchKernelGGL((gat_agg_half<64, false, true>), dim3(ab), blk, 0, stream,
                       HS, HD, attn1, row_start, src_sorted, P, (float*)nullptr, N);

    // ---- Layer 2: fused hs|hd (SPLIT40) + eff residual (f32 -> out); FINAL agg accumulates ----
    hipLaunchKernelGGL((gemm_lds<bf16_t, 2, 256, 192, true, true>), dim3(mtiles), blk, 0, stream,
                       P, t_src2, t_dst2, (const bf16_t*)nullptr, b_src2, b_dst2, (const float*)nullptr,
                       HS, HD, (bf16_t*)nullptr,
                       t_eff, b_eff, out,
                       N, 160);
    hipLaunchKernelGGL((gat_agg_half<40, true, false>), dim3(ab), blk, 0, stream,
                       HS, HD, attn2, row_start, src_sorted, (bf16_t*)nullptr, out, N);
}